// Round 1
// baseline (29.278 us; speedup 1.0000x reference)
//
#include <hip/hip_runtime.h>

#define NS 384
#define NT 384
#define D  256
// 4 waves per block, each wave handles 96 i's = 24 groups of 4
#define WAVES 4
#define GRP_PER_WAVE 24

__device__ __forceinline__ float wave_sum(float v) {
#pragma unroll
    for (int off = 32; off; off >>= 1) v += __shfl_xor(v, off, 64);
    return v;
}

// One block per target t. loss_t = ||S||^2 - 2 * sum_g ||S_g||^2,
// S = sum_i (trgt_t - src_i)/||trgt_t - src_i||, groups g of 4 consecutive i.
__global__ __launch_bounds__(256) void per_t_kernel(
        const float* __restrict__ src, const float* __restrict__ trgt,
        float* __restrict__ partial) {
    const int t    = blockIdx.x;
    const int wave = threadIdx.x >> 6;
    const int lane = threadIdx.x & 63;

    const float4* src4  = (const float4*)src;
    const float4* trgt4 = (const float4*)(trgt + (size_t)t * D);
    const float4  tv    = trgt4[lane];   // lane owns dims [4*lane, 4*lane+4)

    float4 S    = {0.f, 0.f, 0.f, 0.f};
    float  gacc = 0.f;                   // lane-partial of sum_g ||S_g||^2

    const int g0 = wave * GRP_PER_WAVE;
#pragma unroll 4
    for (int g = g0; g < g0 + GRP_PER_WAVE; ++g) {
        float4 Sg = {0.f, 0.f, 0.f, 0.f};
#pragma unroll
        for (int k = 0; k < 4; ++k) {
            const int i = g * 4 + k;
            const float4 sv = src4[(size_t)i * 64 + lane];
            float4 d;
            d.x = tv.x - sv.x; d.y = tv.y - sv.y;
            d.z = tv.z - sv.z; d.w = tv.w - sv.w;
            float ss = d.x*d.x + d.y*d.y + d.z*d.z + d.w*d.w;
            float n2 = wave_sum(ss);          // ||d||^2 broadcast to all lanes
            float rn = rsqrtf(n2);            // norms ~22, EPS never binds
            Sg.x += d.x * rn; Sg.y += d.y * rn;
            Sg.z += d.z * rn; Sg.w += d.w * rn;
        }
        gacc += Sg.x*Sg.x + Sg.y*Sg.y + Sg.z*Sg.z + Sg.w*Sg.w;
        S.x += Sg.x; S.y += Sg.y; S.z += Sg.z; S.w += Sg.w;
    }

    __shared__ float4 sbuf[WAVES][64];
    __shared__ float  gbuf[WAVES][64];
    sbuf[wave][lane] = S;
    gbuf[wave][lane] = gacc;
    __syncthreads();

    if (wave == 0) {
        const float4 a = sbuf[0][lane], b = sbuf[1][lane];
        const float4 c = sbuf[2][lane], e = sbuf[3][lane];
        const float sx = a.x + b.x + c.x + e.x;
        const float sy = a.y + b.y + c.y + e.y;
        const float sz = a.z + b.z + c.z + e.z;
        const float sw = a.w + b.w + c.w + e.w;
        float p = sx*sx + sy*sy + sz*sz + sw*sw;          // lane part of ||S||^2
        float g = gbuf[0][lane] + gbuf[1][lane] + gbuf[2][lane] + gbuf[3][lane];
        float val = wave_sum(p - 2.f * g);
        if (lane == 0) partial[t] = val;
    }
}

__global__ __launch_bounds__(128) void finalize_kernel(
        const float* __restrict__ partial, float* __restrict__ out) {
    __shared__ double buf[128];
    const int tid = threadIdx.x;
    double s = 0.0;
    for (int i = tid; i < NT; i += 128) s += (double)partial[i];
    buf[tid] = s;
    __syncthreads();
    for (int off = 64; off; off >>= 1) {
        if (tid < off) buf[tid] += buf[tid + off];
        __syncthreads();
    }
    if (tid == 0) out[0] = (float)(buf[0] / ((double)NS * NS * NT));
}

extern "C" void kernel_launch(void* const* d_in, const int* in_sizes, int n_in,
                              void* d_out, int out_size, void* d_ws, size_t ws_size,
                              hipStream_t stream) {
    const float* src  = (const float*)d_in[0];   // src_feats  [384, 256] f32
    const float* trgt = (const float*)d_in[1];   // trgt_feats [384, 256] f32
    float* partial = (float*)d_ws;               // 384 floats of scratch
    float* out     = (float*)d_out;

    per_t_kernel<<<NT, 256, 0, stream>>>(src, trgt, partial);
    finalize_kernel<<<1, 128, 0, stream>>>(partial, out);
}

// Round 2
// 27.019 us; speedup vs baseline: 1.0836x; 1.0836x over previous
//
#include <hip/hip_runtime.h>

#define NS 384
#define NT 384
#define D  256
#define NBLK 768            // block = (t, half-of-i); 768 = 3 * 256 CUs exactly
#define GRP_PER_WAVE 12     // 4 waves * 12 groups = 48 groups = half of 96

// reduce within each 32-lane half (offsets never cross the half boundary)
__device__ __forceinline__ float half_sum32(float v) {
#pragma unroll
    for (int off = 16; off; off >>= 1) v += __shfl_xor(v, off, 64);
    return v;
}
__device__ __forceinline__ float wave_sum64(float v) {
#pragma unroll
    for (int off = 32; off; off >>= 1) v += __shfl_xor(v, off, 64);
    return v;
}

// loss_t = ||S_t||^2 - 2 * sum_g ||S_g||^2,  S = sum_i (t - s_i)/||t - s_i||.
// Block b handles t = b>>1, i-range half = b&1 (192 i's = 48 groups).
// Lane owns 8 dims; lanes 0-31 process even i, lanes 32-63 odd i concurrently.
__global__ __launch_bounds__(256) void per_t_kernel(
        const float* __restrict__ src, const float* __restrict__ trgt,
        float* __restrict__ Svec, float* __restrict__ gpart) {
    const int b    = blockIdx.x;
    const int t    = b >> 1;
    const int half = b & 1;
    const int wave = threadIdx.x >> 6;
    const int lane = threadIdx.x & 63;
    const int hl   = lane & 31;   // lane within half: owns dims [8*hl, 8*hl+8)
    const int hi   = lane >> 5;   // 0 -> even i, 1 -> odd i

    const float4* src4 = (const float4*)src;
    const float4* t4   = (const float4*)(trgt + (size_t)t * D);
    const float4  tv0  = t4[2*hl];
    const float4  tv1  = t4[2*hl + 1];

    float4 Sf0 = {0,0,0,0}, Sf1 = {0,0,0,0};   // full S over this block's groups
    float  gacc = 0.f;                          // sum_g ||S_g||^2 (dims duplicated across halves)

    const int g0 = half * 48 + wave * GRP_PER_WAVE;
#pragma unroll 2
    for (int g = g0; g < g0 + GRP_PER_WAVE; ++g) {
        float4 Sg0 = {0,0,0,0}, Sg1 = {0,0,0,0};   // this half's partial of S_g
#pragma unroll
        for (int p = 0; p < 2; ++p) {
            const int i = 4*g + 2*p + hi;
            const float4 sv0 = src4[i*64 + 2*hl];
            const float4 sv1 = src4[i*64 + 2*hl + 1];
            float4 d0, d1;
            d0.x = tv0.x - sv0.x; d0.y = tv0.y - sv0.y;
            d0.z = tv0.z - sv0.z; d0.w = tv0.w - sv0.w;
            d1.x = tv1.x - sv1.x; d1.y = tv1.y - sv1.y;
            d1.z = tv1.z - sv1.z; d1.w = tv1.w - sv1.w;
            float ss = d0.x*d0.x + d0.y*d0.y + d0.z*d0.z + d0.w*d0.w
                     + d1.x*d1.x + d1.y*d1.y + d1.z*d1.z + d1.w*d1.w;
            ss = half_sum32(ss);          // ||d_i||^2 within this 32-lane half
            const float rn = rsqrtf(ss);  // norms ~22; EPS never binds
            Sg0.x += d0.x*rn; Sg0.y += d0.y*rn; Sg0.z += d0.z*rn; Sg0.w += d0.w*rn;
            Sg1.x += d1.x*rn; Sg1.y += d1.y*rn; Sg1.z += d1.z*rn; Sg1.w += d1.w*rn;
        }
        // combine even/odd halves -> full S_g in all lanes (mirror lanes own same dims)
        Sg0.x += __shfl_xor(Sg0.x, 32, 64); Sg0.y += __shfl_xor(Sg0.y, 32, 64);
        Sg0.z += __shfl_xor(Sg0.z, 32, 64); Sg0.w += __shfl_xor(Sg0.w, 32, 64);
        Sg1.x += __shfl_xor(Sg1.x, 32, 64); Sg1.y += __shfl_xor(Sg1.y, 32, 64);
        Sg1.z += __shfl_xor(Sg1.z, 32, 64); Sg1.w += __shfl_xor(Sg1.w, 32, 64);
        gacc += Sg0.x*Sg0.x + Sg0.y*Sg0.y + Sg0.z*Sg0.z + Sg0.w*Sg0.w
              + Sg1.x*Sg1.x + Sg1.y*Sg1.y + Sg1.z*Sg1.z + Sg1.w*Sg1.w;
        Sf0.x += Sg0.x; Sf0.y += Sg0.y; Sf0.z += Sg0.z; Sf0.w += Sg0.w;
        Sf1.x += Sg1.x; Sf1.y += Sg1.y; Sf1.z += Sg1.z; Sf1.w += Sg1.w;
    }

    __shared__ float sS[4][D];
    __shared__ float sG[4];
    if (hi == 0) {   // lanes 0..31 hold the full (even+odd) S for their dims
        *(float4*)&sS[wave][8*hl]     = Sf0;
        *(float4*)&sS[wave][8*hl + 4] = Sf1;
    }
    const float gw = wave_sum64(gacc) * 0.5f;  // dims counted twice across halves
    if (lane == 0) sG[wave] = gw;
    __syncthreads();

    const int tid = threadIdx.x;
    const float s = sS[0][tid] + sS[1][tid] + sS[2][tid] + sS[3][tid];
    Svec[(size_t)b * D + tid] = s;
    if (tid == 0) gpart[b] = sG[0] + sG[1] + sG[2] + sG[3];
}

__global__ __launch_bounds__(256) void finalize_kernel(
        const float* __restrict__ Svec, const float* __restrict__ gpart,
        float* __restrict__ out) {
    const int tid = threadIdx.x, wave = tid >> 6, lane = tid & 63;
    const float4* S4 = (const float4*)Svec;
    float acc = 0.f;                 // lane-partial of sum_t ||S_t||^2 (no shuffles in loop)
#pragma unroll 4
    for (int k = 0; k < 96; ++k) {
        const int t = wave * 96 + k;
        const float4 a = S4[(2*t)*64 + lane];       // half 0
        const float4 c = S4[(2*t + 1)*64 + lane];   // half 1
        float4 s;
        s.x = a.x + c.x; s.y = a.y + c.y; s.z = a.z + c.z; s.w = a.w + c.w;
        acc += s.x*s.x + s.y*s.y + s.z*s.z + s.w*s.w;
    }
    const float g = gpart[tid] + gpart[tid + 256] + gpart[tid + 512];
    float v = wave_sum64(acc - 2.f * g);
    __shared__ float buf[4];
    if (lane == 0) buf[wave] = v;
    __syncthreads();
    if (tid == 0) {
        const double tot = (double)buf[0] + buf[1] + buf[2] + buf[3];
        out[0] = (float)(tot / ((double)NS * NS * NT));
    }
}

extern "C" void kernel_launch(void* const* d_in, const int* in_sizes, int n_in,
                              void* d_out, int out_size, void* d_ws, size_t ws_size,
                              hipStream_t stream) {
    const float* src  = (const float*)d_in[0];   // src_feats  [384, 256] f32
    const float* trgt = (const float*)d_in[1];   // trgt_feats [384, 256] f32
    float* Svec  = (float*)d_ws;                          // [768][256] f32
    float* gpart = (float*)d_ws + (size_t)NBLK * D;       // [768] f32
    float* out   = (float*)d_out;

    per_t_kernel<<<NBLK, 256, 0, stream>>>(src, trgt, Svec, gpart);
    finalize_kernel<<<1, 256, 0, stream>>>(Svec, gpart, out);
}